// Round 4
// baseline (578.380 us; speedup 1.0000x reference)
//
#include <hip/hip_runtime.h>
#include <cstddef>

// ---------------- problem constants ----------------
#define NB 16
#define NC 256
#define NH 32
#define NW 32
#define NK 81

// LDS float offsets (1 block/CU). Stride-36 rows: 9*row = row (mod 8) -> all 8 bank-groups.
#define L_FLT    0        // [256][36]  flt row
#define L_FG     9216     // [256][36]  filter-grad row
#define L_MRES   18432    // [81][36]   mapped residuals (C reuses as sg^2 scratch)
#define L_SMASK  21348    // [81][36]
#define L_FS     24264    // red: 4x2916 = 11664; pass-B pp [128][36] overlays (consumed before reuse)
#define L_CL     36936    // local consts [245]
#define L_ANUM   37184    // [32]
#define L_ALPHA  37216    // [32]
#define L_TOTAL  37248

__device__ __forceinline__ float4 ld4(const float* p) { return *reinterpret_cast<const float4*>(p); }
__device__ __forceinline__ void st4(float* p, float4 v) { *reinterpret_cast<float4*>(p) = v; }

__device__ __forceinline__ void map_by(int bi, int& b, int& y) {
    int xcd = bi & 7, slot = bi >> 3;
    b = xcd * 2 + (slot >> 5);
    y = slot & 31;
}

// Correlation pass: scores(k,x) = sum_c A[c,x]*featpad[c,y+dy,x+dx-4]
// w operand read DIRECT from global (L2-resident feat) -> chunk loop is barrier-free.
// Results left in 4 red buffers at S[L_FS + p*2916] (stride-36 rows), consumer sums the 4.
__device__ __forceinline__ void corr_pass(float* S, const float* __restrict__ gw,
                                          int a_off, int tid,
                                          int lg, int oct, int dyA, bool vry) {
    float acc[9][8];
#pragma unroll
    for (int dx = 0; dx < 9; dx++)
#pragma unroll
        for (int i = 0; i < 8; i++) acc[dx][i] = 0.f;

    if (vry) {
        const int cl0 = lg * 2;
#pragma unroll 2
        for (int chunk = 0; chunk < 8; chunk++) {
#pragma unroll
            for (int j = 0; j < 2; j++) {
                const int cl = chunk * 32 + cl0 + j;
                // A-operand (flt or fg) from LDS — stable region, no sync needed
                const float* fb = S + a_off + cl * 36 + oct * 8;
                float4 f0 = ld4(fb), f1 = ld4(fb + 4);
                // w operand direct from global: x window [oct*8-4, oct*8+12)
                const float* wp = gw + (size_t)cl * (NH * NW);
                float4 w0v = make_float4(0.f, 0.f, 0.f, 0.f);
                float4 w3v = make_float4(0.f, 0.f, 0.f, 0.f);
                if (oct > 0) w0v = ld4(wp);          // x<0 halo -> zeros (skip OOB load)
                float4 w1v = ld4(wp + 4), w2v = ld4(wp + 8);
                if (oct < 3) w3v = ld4(wp + 12);     // x>=32 halo -> zeros
                float w[16] = {w0v.x, w0v.y, w0v.z, w0v.w, w1v.x, w1v.y, w1v.z, w1v.w,
                               w2v.x, w2v.y, w2v.z, w2v.w, w3v.x, w3v.y, w3v.z, w3v.w};
                float f[8] = {f0.x, f0.y, f0.z, f0.w, f1.x, f1.y, f1.z, f1.w};
#pragma unroll
                for (int dx = 0; dx < 9; dx++)
#pragma unroll
                    for (int i = 0; i < 8; i++)
                        acc[dx][i] = fmaf(f[i], w[i + dx], acc[dx][i]);
            }
        }
    }
    // 4-buffer, 4-phase cross-group reduce (stride-36 rows: conflict-free).
    // Order identical to previous kernel -> bitwise-identical sums.
    float* fs = S + L_FS;
#pragma unroll 1
    for (int p = 0; p < 4; p++) {
        if ((lg >> 2) == p) {
            float* Bf = fs + (lg & 3) * 2916;
#pragma unroll
            for (int dx = 0; dx < 9; dx++) {
                int idx = (dyA * 9 + dx) * 36 + oct * 8;
                if (p == 0) {
                    st4(Bf + idx,     make_float4(acc[dx][0], acc[dx][1], acc[dx][2], acc[dx][3]));
                    st4(Bf + idx + 4, make_float4(acc[dx][4], acc[dx][5], acc[dx][6], acc[dx][7]));
                } else {
                    float4 t0 = ld4(Bf + idx), t1 = ld4(Bf + idx + 4);
                    t0.x += acc[dx][0]; t0.y += acc[dx][1]; t0.z += acc[dx][2]; t0.w += acc[dx][3];
                    t1.x += acc[dx][4]; t1.y += acc[dx][5]; t1.z += acc[dx][6]; t1.w += acc[dx][7];
                    st4(Bf + idx, t0); st4(Bf + idx + 4, t1);
                }
            }
        }
        __syncthreads();
    }
}

// ---------------- mega kernel: one block = one (b,y) row, all 3 iterations ----------------
__global__ __launch_bounds__(576, 2) void mega(const float* __restrict__ flt_in,
                                               const float* __restrict__ feat,
                                               float* __restrict__ out,
                                               float* __restrict__ cst_g,
                                               const float* __restrict__ lw,
                                               const float* __restrict__ mw,
                                               const float* __restrict__ sww,
                                               const float* __restrict__ lsl,
                                               const float* __restrict__ fr) {
    __shared__ float S[L_TOTAL];
    int b, y; map_by(blockIdx.x, b, y);
    const int tid = threadIdx.x;

    // A/C compute mapping
    const int lg  = tid / 36;
    const int r36 = tid - lg * 36;
    const int oct = r36 & 3;
    const int dyA = r36 >> 2;
    const int ryA = y + dyA - 4;
    const bool vry = (ryA >= 0 && ryA < 32);
    // per-thread global w base for corr passes (row ryA, x = oct*8-4); deref'd only via +4.. when masked
    const float* gw = feat + (size_t)b * (NC * NH * NW)
                    + (size_t)(vry ? ryA : 0) * NW + oct * 8 - 4;
    // B mapping: oct fastest across lanes -> compact cache-line footprint + conflict-free LDS stores
    const int octB = tid & 3;
    const int cB   = tid >> 2;          // 0..127 for active threads
    const bool actB = (tid < 512);

    // local constants (k_const folded in; per-block LDS-local)
    if (tid < 81) {
        int dyc = tid / 9, dxc = tid - dyc * 9;
        float dist = sqrtf((float)((dyc - 4) * (dyc - 4) + (dxc - 4) * (dxc - 4)));
        float lab = 0.f, mm = 0.f, ss = 0.f;
        for (int d = 0; d < 10; d++) {
            float diff = dist * 2.f - (float)d;
            float bv = (d < 9) ? fmaxf(0.f, 1.f - fabsf(diff))
                               : fminf(fmaxf(1.f + diff, 0.f), 1.f);
            lab += bv * lw[d];
            mm  += bv * mw[d];
            ss  += bv * sww[d];
        }
        S[L_CL + tid]       = lab;
        S[L_CL + 81 + tid]  = 1.f / (1.f + expf(-mm));
        S[L_CL + 162 + tid] = ss;
    } else if (tid == 81) {
        S[L_CL + 243] = expf(lsl[0]);
    } else if (tid == 82) {
        S[L_CL + 244] = fmaxf(fr[0] * fr[0], 1e-10f) * (1.f / 65536.f);
    }
    // stage flt row
    {
        const float* base = flt_in + ((size_t)b * NC * NH + y) * NW;
        for (int i = tid; i < 2048; i += 576) {
            int c = i >> 3, q = i & 7;
            st4(S + L_FLT + c * 36 + q * 4, ld4(base + c * (NH * NW) + q * 4));
        }
    }
    __syncthreads();
    const float step = S[L_CL + 243];
    const float rw   = S[L_CL + 244];

#pragma unroll 1
    for (int it = 0; it < 3; it++) {
        // ---------- pass A: scores = corr(flt), elementwise -> mres/smask, src loss ----------
        corr_pass(S, gw, L_FLT, tid, lg, oct, dyA, vry);

        float srcl = 0.f;
        if (tid < 324) {
            const int kk = tid >> 2, o8 = (tid & 3) * 8;
            const int base = kk * 36 + o8;
            const float lab = S[L_CL + kk], m = S[L_CL + 81 + kk], sw = S[L_CL + 162 + kk];
            const float am = 0.5f * (1.f - m), ap = 0.5f * (1.f + m);
#pragma unroll
            for (int h = 0; h < 2; h++) {
                float4 s0 = ld4(S + L_FS + base + h * 4);
                float4 s1 = ld4(S + L_FS + 2916 + base + h * 4);
                float4 s2 = ld4(S + L_FS + 5832 + base + h * 4);
                float4 s3 = ld4(S + L_FS + 8748 + base + h * 4);
                float sv[4] = {s0.x + s1.x + s2.x + s3.x, s0.y + s1.y + s2.y + s3.y,
                               s0.z + s1.z + s2.z + s3.z, s0.w + s1.w + s2.w + s3.w};
                float tr[4], tm[4];
#pragma unroll
                for (int xi = 0; xi < 4; xi++) {
                    float s = sv[xi];
                    float act = am * fabsf(s) + ap * s;
                    float sgn = (s > 0.f ? 1.f : 0.f) - (s < 0.f ? 1.f : 0.f);
                    float msk = am * sgn + ap;
                    float lres = sw * (act - lab);
                    srcl = fmaf(lres, lres, srcl);
                    tr[xi] = msk * sw * lres;
                    tm[xi] = msk;
                }
                st4(S + L_MRES + base + h * 4,  make_float4(tr[0], tr[1], tr[2], tr[3]));
                st4(S + L_SMASK + base + h * 4, make_float4(tm[0], tm[1], tm[2], tm[3]));
            }
        }
#pragma unroll
        for (int off = 32; off > 0; off >>= 1) srcl += __shfl_down(srcl, off, 64);
        if ((tid & 63) == 0) atomicAdd(cst_g + it, srcl);
        __syncthreads();   // (mres/smask visible; red buffers free for pp overlay)

        // ---------- pass B: fg = corr_T(mres) + rw*flt; alpha_num; reg loss ----------
        // Barrier-free dy loop: w direct from global, mres broadcast from stable LDS.
        {
            float accb[2][8];
#pragma unroll
            for (int j = 0; j < 2; j++)
#pragma unroll
                for (int i = 0; i < 8; i++) accb[j][i] = 0.f;

            const int dy0 = (y < 4) ? (4 - y) : 0;
            const int dyN = (y > 27) ? (36 - y) : 9;
            if (actB) {
#pragma unroll 1
                for (int dy = dy0; dy < dyN; ++dy) {
                    const int ry = y + dy - 4;
                    float rr[9][8];
#pragma unroll
                    for (int dx = 0; dx < 9; dx++) {
                        int mi = (dy * 9 + dx) * 36 + octB * 8;   // 4-way broadcast groups
                        float4 t0 = ld4(S + L_MRES + mi), t1 = ld4(S + L_MRES + mi + 4);
                        rr[dx][0] = t0.x; rr[dx][1] = t0.y; rr[dx][2] = t0.z; rr[dx][3] = t0.w;
                        rr[dx][4] = t1.x; rr[dx][5] = t1.y; rr[dx][6] = t1.z; rr[dx][7] = t1.w;
                    }
#pragma unroll
                    for (int j = 0; j < 2; j++) {
                        const int c = cB + 128 * j;
                        const float* wp = feat + ((size_t)(b * NC + c) * NH + ry) * NW + octB * 8 - 4;
                        float4 w0v = make_float4(0.f, 0.f, 0.f, 0.f);
                        float4 w3v = make_float4(0.f, 0.f, 0.f, 0.f);
                        if (octB > 0) w0v = ld4(wp);
                        float4 w1v = ld4(wp + 4), w2v = ld4(wp + 8);
                        if (octB < 3) w3v = ld4(wp + 12);
                        float w[16] = {w0v.x, w0v.y, w0v.z, w0v.w, w1v.x, w1v.y, w1v.z, w1v.w,
                                       w2v.x, w2v.y, w2v.z, w2v.w, w3v.x, w3v.y, w3v.z, w3v.w};
#pragma unroll
                        for (int dx = 0; dx < 9; dx++)
#pragma unroll
                            for (int i = 0; i < 8; i++)
                                accb[j][i] = fmaf(rr[dx][i], w[i + dx], accb[j][i]);
                    }
                }
            }

            float regl = 0.f;
            if (actB) {
                float g[2][8];
#pragma unroll
                for (int j = 0; j < 2; j++) {
                    const int c = cB + 128 * j;
                    const float* fb = S + L_FLT + c * 36 + octB * 8;
                    float4 f0 = ld4(fb), f1 = ld4(fb + 4);
                    float fv[8] = {f0.x, f0.y, f0.z, f0.w, f1.x, f1.y, f1.z, f1.w};
#pragma unroll
                    for (int i = 0; i < 8; i++) {
                        g[j][i] = accb[j][i] + rw * fv[i];
                        regl = fmaf(fv[i], fv[i], regl);
                    }
                    st4(S + L_FG + c * 36 + octB * 8,
                        make_float4(g[j][0], g[j][1], g[j][2], g[j][3]));
                    st4(S + L_FG + c * 36 + octB * 8 + 4,
                        make_float4(g[j][4], g[j][5], g[j][6], g[j][7]));
                }
                float pp[8];
#pragma unroll
                for (int i = 0; i < 8; i++) pp[i] = g[0][i] * g[0][i] + g[1][i] * g[1][i];
                st4(S + L_FS + cB * 36 + octB * 8,     make_float4(pp[0], pp[1], pp[2], pp[3]));
                st4(S + L_FS + cB * 36 + octB * 8 + 4, make_float4(pp[4], pp[5], pp[6], pp[7]));
            }
#pragma unroll
            for (int off = 32; off > 0; off >>= 1) regl += __shfl_down(regl, off, 64);
            if ((tid & 63) == 0) atomicAdd(cst_g + 3 + it, regl);
            __syncthreads();   // FG + pp visible
            if (tid < 32) {
                float s = 0.f;
                for (int c2 = 0; c2 < 128; c2++) s += S[L_FS + c2 * 36 + tid];
                S[L_ANUM + tid] = s;
            }
            __syncthreads();   // anum done; FS free for corr-C reduce
        }

        // ---------- pass C: sg = corr(fg)*sw*mask; alpha; flt update ----------
        corr_pass(S, gw, L_FG, tid, lg, oct, dyA, vry);

        if (tid < 324) {
            const int kk = tid >> 2, o8 = (tid & 3) * 8;
            const int base = kk * 36 + o8;
            const float sw = S[L_CL + 162 + kk];
#pragma unroll
            for (int h = 0; h < 2; h++) {
                float4 s0 = ld4(S + L_FS + base + h * 4);
                float4 s1 = ld4(S + L_FS + 2916 + base + h * 4);
                float4 s2 = ld4(S + L_FS + 5832 + base + h * 4);
                float4 s3 = ld4(S + L_FS + 8748 + base + h * 4);
                float4 mk = ld4(S + L_SMASK + base + h * 4);
                float sg0 = sw * mk.x * (s0.x + s1.x + s2.x + s3.x);
                float sg1 = sw * mk.y * (s0.y + s1.y + s2.y + s3.y);
                float sg2 = sw * mk.z * (s0.z + s1.z + s2.z + s3.z);
                float sg3 = sw * mk.w * (s0.w + s1.w + s2.w + s3.w);
                st4(S + L_MRES + base + h * 4,   // mres dead -> sg^2 scratch
                    make_float4(sg0 * sg0, sg1 * sg1, sg2 * sg2, sg3 * sg3));
            }
        }
        __syncthreads();
        if (tid < 32) {
            float den = 0.f;
            for (int k = 0; k < 81; k++) den += S[L_MRES + k * 36 + tid];
            float num = S[L_ANUM + tid];
            float dd = fmaxf(den + rw * num, 1e-8f);
            S[L_ALPHA + tid] = step * num / dd;
        }
        __syncthreads();
        for (int i = tid; i < 2048; i += 576) {
            int c = i >> 3, q = i & 7;
            float* fp = S + L_FLT + c * 36 + q * 4;
            float4 fl = ld4(fp);
            float4 g = ld4(S + L_FG + c * 36 + q * 4);
            float4 al = ld4(S + L_ALPHA + q * 4);
            fl.x -= al.x * g.x;
            fl.y -= al.y * g.y;
            fl.z -= al.z * g.z;
            fl.w -= al.w * g.w;
            st4(fp, fl);
        }
        __syncthreads();
    }

    // final: write flt row to output
    for (int i = tid; i < 2048; i += 576) {
        int c = i >> 3, q = i & 7;
        st4(out + ((size_t)(b * NC + c) * NH + y) * NW + q * 4,
            ld4(S + L_FLT + c * 36 + q * 4));
    }
}

// ---------------- tail: write tr, tr_src, tr_reg (separate dispatch, no fences in mega) ----------------
__global__ void k_tail(const float* __restrict__ cst, const float* __restrict__ fr,
                       float* __restrict__ out) {
    int i = threadIdx.x;
    if (i < 3) {
        float rw = fmaxf(fr[0] * fr[0], 1e-10f) * (1.f / 65536.f);
        float src = 0.5f * cst[i] / 16.f;
        float reg = 0.5f * rw * cst[3 + i] / 16.f;
        out[4194304 + i] = src + reg;
        out[4194307 + i] = src;
        out[4194310 + i] = reg;
    }
}

extern "C" void kernel_launch(void* const* d_in, const int* in_sizes, int n_in,
                              void* d_out, int out_size, void* d_ws, size_t ws_size,
                              hipStream_t stream) {
    (void)in_sizes; (void)n_in; (void)out_size; (void)ws_size;
    const float* flt_in = (const float*)d_in[0];
    const float* feat   = (const float*)d_in[1];
    const float* lw     = (const float*)d_in[2];
    const float* mw     = (const float*)d_in[3];
    const float* sww    = (const float*)d_in[4];
    const float* lsl    = (const float*)d_in[5];
    const float* fr     = (const float*)d_in[6];
    float* out = (float*)d_out;
    float* cst = (float*)d_ws;

    hipMemsetAsync(cst, 0, 32, stream);   // src[3], reg[3]
    mega<<<512, 576, 0, stream>>>(flt_in, feat, out, cst, lw, mw, sww, lsl, fr);
    k_tail<<<1, 64, 0, stream>>>(cst, fr, out);
}